// Round 1
// baseline (317.660 us; speedup 1.0000x reference)
//
#include <hip/hip_runtime.h>
#include <hip/hip_bf16.h>
#include <math.h>

#define N_NODES 32768
#define N_EDGES 262144
#define EPS_C 0.24253562503633297f   // 1/sqrt(17)
#define NSPEC 10

typedef __attribute__((ext_vector_type(8))) short short8;   // 8 bf16
typedef __attribute__((ext_vector_type(4))) float f32x4;    // 4 fp32 acc

#define MFMA16(a, b, c) __builtin_amdgcn_mfma_f32_16x16x32_bf16(a, b, c, 0, 0, 0)

__device__ __forceinline__ short2 cvt2(float a, float b) {
    union { __hip_bfloat162 h; short2 s; } u;
    u.h = __float22bfloat162_rn(make_float2(a, b));
    return u.s;
}
__device__ __forceinline__ unsigned short f2bf(float a) {
    return (unsigned short)cvt2(a, 0.f).x;
}
__device__ __forceinline__ float bf2f(unsigned short u) {
    return __uint_as_float(((unsigned)u) << 16);
}
__device__ __forceinline__ short8 cvt8(float4 a, float4 b) {
    short2 p0 = cvt2(a.x, a.y), p1 = cvt2(a.z, a.w);
    short2 p2 = cvt2(b.x, b.y), p3 = cvt2(b.z, b.w);
    short8 r;
    r[0] = p0.x; r[1] = p0.y; r[2] = p1.x; r[3] = p1.y;
    r[4] = p2.x; r[5] = p2.y; r[6] = p3.x; r[7] = p3.y;
    return r;
}
__device__ __forceinline__ short8 loadArow(const float* rowp, int h, int q) {
    const float* p = rowp + h * 32 + q * 8;
    return cvt8(*(const float4*)p, *(const float4*)(p + 4));
}
__device__ __forceinline__ short8 loadB(const short* P, int t, int h, int l) {
    return *(const short8*)(P + (((t * 2 + h) * 64 + l) << 3));
}

// ---------------------------------------------------------------------------
// Species counting sort — contention-free, deterministic. sort1 also zeroes
// the receiver-CSR counts array.
// ---------------------------------------------------------------------------
__global__ __launch_bounds__(256) void sort1_kernel(
    const int* __restrict__ species, int* __restrict__ counts_blk,
    int* __restrict__ lrank_arr, int* __restrict__ counts)
{
    __shared__ int wcnt[4][16];
    int n = blockIdx.x * 256 + threadIdx.x;
    counts[n] = 0;
    int sp = species[n];
    int lane = threadIdx.x & 63, wv = threadIdx.x >> 6;
    unsigned long long ltmask = (1ull << lane) - 1;
    int lrank_w = 0;
#pragma unroll
    for (int z = 0; z < NSPEC; ++z) {
        unsigned long long m = __ballot(sp == z);
        if (sp == z) lrank_w = __popcll(m & ltmask);
        if (lane == 0) wcnt[wv][z] = __popcll(m);
    }
    __syncthreads();
    int off = 0;
    for (int w = 0; w < wv; ++w) off += wcnt[w][sp];
    lrank_arr[n] = lrank_w + off;
    if (threadIdx.x < NSPEC)
        counts_blk[blockIdx.x * NSPEC + threadIdx.x] =
            wcnt[0][threadIdx.x] + wcnt[1][threadIdx.x] +
            wcnt[2][threadIdx.x] + wcnt[3][threadIdx.x];
}

// parallel block-offset scan: wave z shuffle-scans its 128 block counts
__global__ __launch_bounds__(640) void sort2_kernel(
    const int* __restrict__ counts_blk, int* __restrict__ off_blk)
{
    __shared__ int totals[16];
    int wv = threadIdx.x >> 6;        // 0..9 == species z
    int lane = threadIdx.x & 63;
    int c0 = counts_blk[lane * NSPEC + wv];
    int c1 = counts_blk[(64 + lane) * NSPEC + wv];
    int s0 = c0;
#pragma unroll
    for (int off = 1; off < 64; off <<= 1) {
        int y = __shfl_up(s0, off);
        if (lane >= off) s0 += y;
    }
    int tot0 = __shfl(s0, 63);
    int s1 = c1;
#pragma unroll
    for (int off = 1; off < 64; off <<= 1) {
        int y = __shfl_up(s1, off);
        if (lane >= off) s1 += y;
    }
    s1 += tot0;
    if (lane == 63) totals[wv] = s1;
    __syncthreads();
    int base = 0;
    for (int q = 0; q < wv; ++q) base += totals[q];
    off_blk[lane * NSPEC + wv] = base + s0 - c0;
    off_blk[(64 + lane) * NSPEC + wv] = base + s1 - c1;
}

__global__ __launch_bounds__(256) void sort3_kernel(
    const int* __restrict__ species, const int* __restrict__ lrank_arr,
    const int* __restrict__ off_blk,
    int* __restrict__ sidx, int* __restrict__ rank, int* __restrict__ spec_srt)
{
    int n = blockIdx.x * 256 + threadIdx.x;
    int sp = species[n];
    int slot = off_blk[blockIdx.x * NSPEC + sp] + lrank_arr[n];
    sidx[slot] = n;
    rank[n] = slot;
    spec_srt[slot] = sp;
}

// ---------------------------------------------------------------------------
// Receiver CSR in SORTED space
// ---------------------------------------------------------------------------
__global__ __launch_bounds__(256) void hist_kernel(
    const int* __restrict__ receivers, const int* __restrict__ rank,
    int* __restrict__ counts)
{
    int e = blockIdx.x * 256 + threadIdx.x;
    atomicAdd(&counts[rank[receivers[e]]], 1);
}

__global__ __launch_bounds__(1024) void scan_kernel(
    const int* __restrict__ counts, int* __restrict__ row_start, int* __restrict__ cursor)
{
    __shared__ int wave_tot[16];
    int tid = threadIdx.x;
    int c[32];
    int sum = 0;
#pragma unroll
    for (int i = 0; i < 32; ++i) { c[i] = counts[tid * 32 + i]; sum += c[i]; }
    int lane = tid & 63, wv = tid >> 6;
    int x = sum;
#pragma unroll
    for (int off = 1; off < 64; off <<= 1) {
        int y = __shfl_up(x, off);
        if (lane >= off) x += y;
    }
    if (lane == 63) wave_tot[wv] = x;
    __syncthreads();
    if (wv == 0 && lane < 16) {
        int t = wave_tot[lane];
#pragma unroll
        for (int off = 1; off < 16; off <<= 1) {
            int y = __shfl_up(t, off);
            if (lane >= off) t += y;
        }
        wave_tot[lane] = t;
    }
    __syncthreads();
    int excl = x - sum + (wv ? wave_tot[wv - 1] : 0);
    int run = excl;
#pragma unroll
    for (int i = 0; i < 32; ++i) {
        row_start[tid * 32 + i] = run;
        cursor[tid * 32 + i] = run;
        run += c[i];
    }
    if (tid == 1023) row_start[32768] = run;
}

__global__ __launch_bounds__(256) void scatter_kernel(
    const int* __restrict__ receivers, const int* __restrict__ rank,
    int* __restrict__ cursor, int* __restrict__ edge_ids)
{
    int e = blockIdx.x * 256 + threadIdx.x;
    int slot = atomicAdd(&cursor[rank[receivers[e]]], 1);
    edge_ids[slot] = e;
}

// ---------------------------------------------------------------------------
// Edge precompute in slot order + fused sender-rank/species stream + grp_row.
// srk[p] = rank | (species << 16)
// ---------------------------------------------------------------------------
__global__ __launch_bounds__(256) void edge_pre_kernel(
    const float* __restrict__ vectors, const int* __restrict__ edge_ids,
    const int* __restrict__ senders, const int* __restrict__ rank,
    const int* __restrict__ species, const int* __restrict__ row_start,
    float* __restrict__ edata, int* __restrict__ srk, int* __restrict__ grp_row)
{
    int p = blockIdx.x * 256 + threadIdx.x;
    int e = edge_ids[p];
    int snd = senders[e];
    srk[p] = rank[snd] | (species[snd] << 16);
    float x = vectors[e * 3 + 0], y = vectors[e * 3 + 1], z = vectors[e * 3 + 2];
    float r2 = x * x + y * y + z * z + 1e-12f;
    float r = sqrtf(r2);
    float inv = 1.0f / r;
    float* d = edata + (size_t)p * 16;
    *(float4*)d = make_float4(x * inv, y * inv, z * inv, 0.0f);
    float rc = fmaxf(r, 1e-6f);
    float r6 = r2 * r2 * r2;
    float r7 = r6 * r;
    float r8 = r6 * r2;
    float env = (r < 1.0f) ? (1.0f - 28.0f * r6 + 48.0f * r7 - 21.0f * r8) : 0.0f;
    float sc = 1.41421356237309515f * env / rc;
#pragma unroll
    for (int j = 0; j < 8; ++j)
        d[4 + j] = sc * sinf((float)(j + 1) * 3.14159265358979323846f * rc);
    d[12] = 0.f; d[13] = 0.f; d[14] = 0.f; d[15] = 0.f;

    if (p < N_EDGES / 16) {
        int target = p * 16;
        int lo = 0, hi = N_NODES - 1;
        while (lo < hi) {
            int mid = (lo + hi + 1) >> 1;
            if (row_start[mid] <= target) lo = mid; else hi = mid - 1;
        }
        grp_row[p] = lo;
    }
}

// ---------------------------------------------------------------------------
// Merged prep: weight pack (blocks<448) + zero_bnd for interaction 0.
// ---------------------------------------------------------------------------
__global__ __launch_bounds__(256) void prep_kernel(
    const float* __restrict__ Wls, const float* __restrict__ Wlv,
    const float* __restrict__ Wps, const float* __restrict__ Wpv,
    const float* __restrict__ skip_s, const float* __restrict__ skip_v,
    short* __restrict__ packW,
    const int* __restrict__ row_start,
    float* __restrict__ agg_s, float* __restrict__ agg_v)
{
    int idx = blockIdx.x * 256 + threadIdx.x;
    if (blockIdx.x < 448 && idx < 28 * 4096) {
        int m = idx >> 12, e = idx & 4095;
        int t = e >> 10, h = (e >> 9) & 1, l = (e >> 3) & 63, j = e & 7;
        int fi = h * 32 + ((l >> 4) << 3) + j;
        int fo = t * 16 + (l & 15);
        const float* src;
        if      (m < 2)  src = Wls    + m * 4096;
        else if (m < 4)  src = Wlv    + (m - 2) * 4096;
        else if (m < 6)  src = Wps    + (m - 4) * 4096;
        else if (m < 8)  src = Wpv    + (m - 6) * 4096;
        else if (m < 18) src = skip_s + (m - 8) * 4096;
        else             src = skip_v + (m - 18) * 4096;
        packW[idx] = cvt2(src[fi * 64 + fo], 0.f).x;
    }
    const int wid = threadIdx.x >> 6;
    const int f = threadIdx.x & 63;
    const int base = (blockIdx.x * 4 + wid) * 4;
#pragma unroll
    for (int t = 0; t < 4; ++t) {
        int i = base + t;
        int beg = row_start[i], end = row_start[i + 1];
        bool need = (end == beg) || (end > (((beg >> 4) + 1) << 4));
        if (need) {
            agg_s[(size_t)i * 64 + f] = 0.f;
            agg_v[((size_t)i * 3 + 0) * 64 + f] = 0.f;
            agg_v[((size_t)i * 3 + 1) * 64 + f] = 0.f;
            agg_v[((size_t)i * 3 + 2) * 64 + f] = 0.f;
        }
    }
}

// ---------------------------------------------------------------------------
// Dual-chain edge-balanced gather (rolled loop, 4 waves/block).
// Per-wave work identical to the 1-wave version; packing 4 independent waves
// per workgroup lifts the workgroup-per-CU occupancy cap (1-wave blocks cap
// at ~16 wg/CU = 50%; measured 36%). No LDS, no cross-wave interaction.
// VZERO: s from 2.5KB embed table. !VZERO: s/v state is bf16 — half the
// random traffic (one 128B line per component per wave).
// ---------------------------------------------------------------------------
template<int VZERO>
__global__ __launch_bounds__(256) void gather_kernel(
    const float* __restrict__ edata, const int* __restrict__ srk,
    const int* __restrict__ row_start, const int* __restrict__ grp_row,
    const float* __restrict__ embed_s,
    const unsigned short* __restrict__ s_in, const unsigned short* __restrict__ v_in,
    const float* __restrict__ Wr_i,
    float* __restrict__ agg_s, float* __restrict__ agg_v)
{
    const int f = threadIdx.x & 63;
    const int w = blockIdx.x * 4 + (threadIdx.x >> 6);
    const int pA0 = w * 32;
    const int pB0 = pA0 + 16;

    float wr[5][8];
#pragma unroll
    for (int j = 0; j < 8; ++j)
#pragma unroll
        for (int p = 0; p < 5; ++p)
            wr[p][j] = (VZERO && (p == 1 || p == 3 || p == 4))
                       ? 0.f : Wr_i[j * 320 + p * 64 + f];

    int rA = grp_row[2 * w], rB = grp_row[2 * w + 1];
    int begA = row_start[rA], endA = row_start[rA + 1];
    int begB = row_start[rB], endB = row_start[rB + 1];
    float aA0 = 0.f, aA1 = 0.f, aA2 = 0.f, aA3 = 0.f;
    float aB0 = 0.f, aB1 = 0.f, aB2 = 0.f, aB3 = 0.f;

    int svA_c = srk[pA0],     svB_c = srk[pB0];
    int svA_n = srk[pA0 + 1], svB_n = srk[pB0 + 1];
    int srA_c = svA_c & 0xFFFF, srB_c = svB_c & 0xFFFF;
    float ssA, ssB;
    if (VZERO) {
        ssA = embed_s[(svA_c >> 16) * 64 + f];
        ssB = embed_s[(svB_c >> 16) * 64 + f];
    } else {
        ssA = bf2f(s_in[(size_t)srA_c * 64 + f]);
        ssB = bf2f(s_in[(size_t)srB_c * 64 + f]);
    }
    float vA0 = 0.f, vA1 = 0.f, vA2 = 0.f, vB0 = 0.f, vB1 = 0.f, vB2 = 0.f;
    if (!VZERO) {
        vA0 = bf2f(v_in[((size_t)srA_c * 3 + 0) * 64 + f]);
        vA1 = bf2f(v_in[((size_t)srA_c * 3 + 1) * 64 + f]);
        vA2 = bf2f(v_in[((size_t)srA_c * 3 + 2) * 64 + f]);
        vB0 = bf2f(v_in[((size_t)srB_c * 3 + 0) * 64 + f]);
        vB1 = bf2f(v_in[((size_t)srB_c * 3 + 1) * 64 + f]);
        vB2 = bf2f(v_in[((size_t)srB_c * 3 + 2) * 64 + f]);
    }

    for (int k = 0; k < 16; ++k) {
        int pA = pA0 + k, pB = pB0 + k;
        int svA_n2 = (k + 2 < 16) ? srk[pA + 2] : svA_n;
        int svB_n2 = (k + 2 < 16) ? srk[pB + 2] : svB_n;
        int srA_n = svA_n & 0xFFFF, srB_n = svB_n & 0xFFFF;
        float ssA_n, ssB_n;
        if (VZERO) {
            ssA_n = embed_s[(svA_n >> 16) * 64 + f];
            ssB_n = embed_s[(svB_n >> 16) * 64 + f];
        } else {
            ssA_n = bf2f(s_in[(size_t)srA_n * 64 + f]);
            ssB_n = bf2f(s_in[(size_t)srB_n * 64 + f]);
        }
        float vA0n = 0.f, vA1n = 0.f, vA2n = 0.f;
        float vB0n = 0.f, vB1n = 0.f, vB2n = 0.f;
        if (!VZERO) {
            vA0n = bf2f(v_in[((size_t)srA_n * 3 + 0) * 64 + f]);
            vA1n = bf2f(v_in[((size_t)srA_n * 3 + 1) * 64 + f]);
            vA2n = bf2f(v_in[((size_t)srA_n * 3 + 2) * 64 + f]);
            vB0n = bf2f(v_in[((size_t)srB_n * 3 + 0) * 64 + f]);
            vB1n = bf2f(v_in[((size_t)srB_n * 3 + 1) * 64 + f]);
            vB2n = bf2f(v_in[((size_t)srB_n * 3 + 2) * 64 + f]);
        }
        const float* dA = edata + (size_t)pA * 16;
        const float* dB = edata + (size_t)pB * 16;
        float4 yA = *(const float4*)dA;
        float4 qA0 = *(const float4*)(dA + 4);
        float4 qA1 = *(const float4*)(dA + 8);
        float4 yB = *(const float4*)dB;
        float4 qB0 = *(const float4*)(dB + 4);
        float4 qB1 = *(const float4*)(dB + 8);

        float rbA[8] = {qA0.x, qA0.y, qA0.z, qA0.w, qA1.x, qA1.y, qA1.z, qA1.w};
        float rbB[8] = {qB0.x, qB0.y, qB0.z, qB0.w, qB1.x, qB1.y, qB1.z, qB1.w};
        float wA0 = 0.f, wA1 = 0.f, wA2 = 0.f, wA3 = 0.f, wA4 = 0.f;
        float wB0 = 0.f, wB1 = 0.f, wB2 = 0.f, wB3 = 0.f, wB4 = 0.f;
#pragma unroll
        for (int j = 0; j < 8; ++j) {
            wA0 = fmaf(rbA[j], wr[0][j], wA0);  wB0 = fmaf(rbB[j], wr[0][j], wB0);
            if (!VZERO) { wA1 = fmaf(rbA[j], wr[1][j], wA1);  wB1 = fmaf(rbB[j], wr[1][j], wB1); }
            wA2 = fmaf(rbA[j], wr[2][j], wA2);  wB2 = fmaf(rbB[j], wr[2][j], wB2);
            if (!VZERO) { wA3 = fmaf(rbA[j], wr[3][j], wA3);  wB3 = fmaf(rbB[j], wr[3][j], wB3); }
            if (!VZERO) { wA4 = fmaf(rbA[j], wr[4][j], wA4);  wB4 = fmaf(rbB[j], wr[4][j], wB4); }
        }
        if (VZERO) {
            aA0 += wA0 * ssA;
            float wsA = wA2 * ssA;
            aA1 += wsA * yA.x; aA2 += wsA * yA.y; aA3 += wsA * yA.z;
            aB0 += wB0 * ssB;
            float wsB = wB2 * ssB;
            aB1 += wsB * yB.x; aB2 += wsB * yB.y; aB3 += wsB * yB.z;
        } else {
            float dotA = vA0 * yA.x + vA1 * yA.y + vA2 * yA.z;
            aA0 += wA0 * ssA + wA1 * dotA;
            float cA0 = vA1 * yA.z - vA2 * yA.y;
            float cA1 = vA2 * yA.x - vA0 * yA.z;
            float cA2 = vA0 * yA.y - vA1 * yA.x;
            float wsA = wA2 * ssA;
            aA1 += wsA * yA.x + wA3 * vA0 + wA4 * cA0;
            aA2 += wsA * yA.y + wA3 * vA1 + wA4 * cA1;
            aA3 += wsA * yA.z + wA3 * vA2 + wA4 * cA2;
            float dotB = vB0 * yB.x + vB1 * yB.y + vB2 * yB.z;
            aB0 += wB0 * ssB + wB1 * dotB;
            float cB0 = vB1 * yB.z - vB2 * yB.y;
            float cB1 = vB2 * yB.x - vB0 * yB.z;
            float cB2 = vB0 * yB.y - vB1 * yB.x;
            float wsB = wB2 * ssB;
            aB1 += wsB * yB.x + wB3 * vB0 + wB4 * cB0;
            aB2 += wsB * yB.y + wB3 * vB1 + wB4 * cB1;
            aB3 += wsB * yB.z + wB3 * vB2 + wB4 * cB2;
        }

        if (pA + 1 == endA || k == 15) {
            bool interior = (begA >= pA0) && (endA <= pA0 + 16);
            if (interior) {
                agg_s[(size_t)rA * 64 + f] = aA0;
                agg_v[((size_t)rA * 3 + 0) * 64 + f] = aA1;
                agg_v[((size_t)rA * 3 + 1) * 64 + f] = aA2;
                agg_v[((size_t)rA * 3 + 2) * 64 + f] = aA3;
            } else {
                unsafeAtomicAdd(&agg_s[(size_t)rA * 64 + f], aA0);
                unsafeAtomicAdd(&agg_v[((size_t)rA * 3 + 0) * 64 + f], aA1);
                unsafeAtomicAdd(&agg_v[((size_t)rA * 3 + 1) * 64 + f], aA2);
                unsafeAtomicAdd(&agg_v[((size_t)rA * 3 + 2) * 64 + f], aA3);
            }
            aA0 = aA1 = aA2 = aA3 = 0.f;
            if (pA + 1 == endA && k < 15) {
                begA = endA; ++rA; endA = row_start[rA + 1];
                while (endA == begA) { ++rA; endA = row_start[rA + 1]; }
            }
        }
        if (pB + 1 == endB || k == 15) {
            bool interior = (begB >= pB0) && (endB <= pB0 + 16);
            if (interior) {
                agg_s[(size_t)rB * 64 + f] = aB0;
                agg_v[((size_t)rB * 3 + 0) * 64 + f] = aB1;
                agg_v[((size_t)rB * 3 + 1) * 64 + f] = aB2;
                agg_v[((size_t)rB * 3 + 2) * 64 + f] = aB3;
            } else {
                unsafeAtomicAdd(&agg_s[(size_t)rB * 64 + f], aB0);
                unsafeAtomicAdd(&agg_v[((size_t)rB * 3 + 0) * 64 + f], aB1);
                unsafeAtomicAdd(&agg_v[((size_t)rB * 3 + 1) * 64 + f], aB2);
                unsafeAtomicAdd(&agg_v[((size_t)rB * 3 + 2) * 64 + f], aB3);
            }
            aB0 = aB1 = aB2 = aB3 = 0.f;
            if (pB + 1 == endB && k < 15) {
                begB = endB; ++rB; endB = row_start[rB + 1];
                while (endB == begB) { ++rB; endB = row_start[rB + 1]; }
            }
        }
        ssA = ssA_n; vA0 = vA0n; vA1 = vA1n; vA2 = vA2n;
        ssB = ssB_n; vB0 = vB0n; vB1 = vB1n; vB2 = vB2n;
        srA_c = srA_n; srB_c = srB_n;
        svA_n = svA_n2; svB_n = svB_n2;
    }
}

// ---------------------------------------------------------------------------
// MFMA node kernel, bf16 s/v state: skip A-fragments are direct short8 loads
// (bit-exact vs fp32 path); s/v stores are RNE-bf16. Fused readout uses
// pre-rounded fp32 registers. wave = 16 sorted nodes.
// ---------------------------------------------------------------------------
__global__ __launch_bounds__(256) void node_mfma_kernel(
    const float* __restrict__ agg_s, const float* __restrict__ agg_v,
    unsigned short* s, unsigned short* v,
    const short* __restrict__ packW, int it,
    const float* __restrict__ pw_i,
    const int* __restrict__ spec_srt,
    const int* __restrict__ row_start, const int* __restrict__ sidx,
    const float* __restrict__ Wread0, const float* __restrict__ Wr1a,
    const float* __restrict__ Wr1b,
    float* __restrict__ out,
    int has_skip)
{
    const int l = threadIdx.x & 63;
    const int wid = threadIdx.x >> 6;
    const int cl = l & 15;
    const int q = l >> 4;
    const int i16 = (blockIdx.x * 4 + wid) * 16;
    __shared__ float xls_all[4][16 * 65];
    float* xls = xls_all[wid];

    const short* pWls = packW + (size_t)(0 + it) * 4096;
    const short* pWlv = packW + (size_t)(2 + it) * 4096;
    const short* pWps = packW + (size_t)(4 + it) * 4096;
    const short* pWpv = packW + (size_t)(6 + it) * 4096;
    const short* pSkS = packW + (size_t)8 * 4096;
    const short* pSkV = packW + (size_t)18 * 4096;
    const short8 z8 = {0, 0, 0, 0, 0, 0, 0, 0};

    const float* ars = agg_s + (size_t)(i16 + cl) * 64;
    short8 As[2] = { loadArow(ars, 0, q), loadArow(ars, 1, q) };
    short8 Av[3][2];
#pragma unroll
    for (int k = 0; k < 3; ++k) {
        const float* r = agg_v + ((size_t)(i16 + cl) * 3 + k) * 64;
        Av[k][0] = loadArow(r, 0, q);
        Av[k][1] = loadArow(r, 1, q);
    }

    f32x4 sD[4];
#pragma unroll
    for (int t = 0; t < 4; ++t) {
        f32x4 acc = {0.f, 0.f, 0.f, 0.f};
        acc = MFMA16(As[0], loadB(pWls, t, 0, l), acc);
        acc = MFMA16(As[1], loadB(pWls, t, 1, l), acc);
        sD[t] = acc;
    }

    f32x4 vD[3][4];
#pragma unroll
    for (int k = 0; k < 3; ++k)
#pragma unroll
        for (int t = 0; t < 4; ++t) vD[k][t] = (f32x4){0.f, 0.f, 0.f, 0.f};
#pragma unroll
    for (int t = 0; t < 4; ++t)
#pragma unroll
        for (int h = 0; h < 2; ++h) {
            short8 b = loadB(pWlv, t, h, l);
#pragma unroll
            for (int k = 0; k < 3; ++k) vD[k][t] = MFMA16(Av[k][h], b, vD[k][t]);
        }

    int z0 = spec_srt[i16], z1 = spec_srt[i16 + 15];
    float psD[4][4], pvsD[4][4];
    if (z0 == z1) {
        const float* pb = pw_i + z0 * 576 + cl;
        float pc[9][4];
#pragma unroll
        for (int c = 0; c < 9; ++c)
#pragma unroll
            for (int t = 0; t < 4; ++t) pc[c][t] = pb[c * 64 + t * 16];
#pragma unroll
        for (int t = 0; t < 4; ++t)
#pragma unroll
            for (int r = 0; r < 4; ++r) {
                float x = sD[t][r] * EPS_C;
                float w0 = vD[0][t][r] * EPS_C;
                float w1 = vD[1][t][r] * EPS_C;
                float w2 = vD[2][t][r] * EPS_C;
                vD[0][t][r] = w0; vD[1][t][r] = w1; vD[2][t][r] = w2;
                float vv = w0 * w0 + w1 * w1 + w2 * w2;
                float x2 = x * x;
                psD[t][r] = pc[0][t] * x + pc[1][t] * x2 + pc[2][t] * vv
                          + pc[3][t] * x2 * x + pc[4][t] * x * vv;
                pvsD[t][r] = pc[5][t] + pc[6][t] * x + pc[7][t] * x2 + pc[8][t] * vv;
            }
    } else {
#pragma unroll
        for (int r = 0; r < 4; ++r) {
            int z = spec_srt[i16 + q * 4 + r];
            const float* pb = pw_i + z * 576 + cl;
#pragma unroll
            for (int t = 0; t < 4; ++t) {
                float p0 = pb[t*16], p1 = pb[64+t*16], p2 = pb[128+t*16];
                float p3 = pb[192+t*16], p4 = pb[256+t*16], p5 = pb[320+t*16];
                float p6 = pb[384+t*16], p7 = pb[448+t*16], p8 = pb[512+t*16];
                float x = sD[t][r] * EPS_C;
                float w0 = vD[0][t][r] * EPS_C;
                float w1 = vD[1][t][r] * EPS_C;
                float w2 = vD[2][t][r] * EPS_C;
                vD[0][t][r] = w0; vD[1][t][r] = w1; vD[2][t][r] = w2;
                float vv = w0 * w0 + w1 * w1 + w2 * w2;
                float x2 = x * x;
                psD[t][r] = p0 * x + p1 * x2 + p2 * vv + p3 * x2 * x + p4 * x * vv;
                pvsD[t][r] = p5 + p6 * x + p7 * x2 + p8 * vv;
            }
        }
    }

#pragma unroll
    for (int t = 0; t < 4; ++t)
#pragma unroll
        for (int r = 0; r < 4; ++r)
            xls[(q * 4 + r) * 65 + t * 16 + cl] = psD[t][r];
    short8 psA[2];
#pragma unroll
    for (int h = 0; h < 2; ++h) {
        const float* rp = xls + cl * 65 + h * 32 + q * 8;
        float t0 = rp[0], t1 = rp[1], t2 = rp[2], t3 = rp[3];
        float t4 = rp[4], t5 = rp[5], t6 = rp[6], t7 = rp[7];
        psA[h] = cvt8(make_float4(t0, t1, t2, t3), make_float4(t4, t5, t6, t7));
    }

    f32x4 snD[4];
#pragma unroll
    for (int t = 0; t < 4; ++t) {
        f32x4 acc = {0.f, 0.f, 0.f, 0.f};
        acc = MFMA16(psA[0], loadB(pWps, t, 0, l), acc);
        acc = MFMA16(psA[1], loadB(pWps, t, 1, l), acc);
        snD[t] = acc;
    }
    if (has_skip) {
        const unsigned short* srow = s + (size_t)(i16 + cl) * 64;
        short8 Ai0 = *(const short8*)(srow + q * 8);
        short8 Ai1 = *(const short8*)(srow + 32 + q * 8);
        int myz = spec_srt[i16 + cl];
        for (int z = z0; z <= z1; ++z) {
            bool keep = (myz == z);
            short8 m0 = keep ? Ai0 : z8;
            short8 m1 = keep ? Ai1 : z8;
            const short* pz = pSkS + (size_t)z * 4096;
#pragma unroll
            for (int t = 0; t < 4; ++t) {
                snD[t] = MFMA16(m0, loadB(pz, t, 0, l), snD[t]);
                snD[t] = MFMA16(m1, loadB(pz, t, 1, l), snD[t]);
            }
        }
    }
#pragma unroll
    for (int t = 0; t < 4; ++t)
#pragma unroll
        for (int r = 0; r < 4; ++r)
            s[(size_t)(i16 + q * 4 + r) * 64 + t * 16 + cl] = f2bf(snD[t][r]);

    // ---- fused readout (pre-rounded fp32 registers)
    if (it == 0) {
        float w0c[4];
#pragma unroll
        for (int t = 0; t < 4; ++t) w0c[t] = Wread0[t * 16 + cl];
#pragma unroll
        for (int r = 0; r < 4; ++r) {
            float a = snD[0][r] * w0c[0] + snD[1][r] * w0c[1]
                    + snD[2][r] * w0c[2] + snD[3][r] * w0c[3];
            a += __shfl_down(a, 8);
            a += __shfl_down(a, 4);
            a += __shfl_down(a, 2);
            a += __shfl_down(a, 1);
            if (cl == 0) out[(size_t)sidx[i16 + q * 4 + r] * 2 + 0] = a;
        }
    } else {
#pragma unroll
        for (int t = 0; t < 4; ++t)
#pragma unroll
            for (int r = 0; r < 4; ++r)
                xls[(q * 4 + r) * 65 + t * 16 + cl] = snD[t][r];
        float acc4[4] = {0.f, 0.f, 0.f, 0.f};
        for (int g = 0; g < 64; ++g) {
            float wa = Wr1a[g * 16 + cl];
#pragma unroll
            for (int j = 0; j < 4; ++j)
                acc4[j] = fmaf(xls[(q + 4 * j) * 65 + g], wa, acc4[j]);
        }
        float wb = Wr1b[cl];
#pragma unroll
        for (int j = 0; j < 4; ++j) {
            float av = acc4[j];
            float rr = (av / (1.f + expf(-av))) * wb;
            rr += __shfl_down(rr, 8);
            rr += __shfl_down(rr, 4);
            rr += __shfl_down(rr, 2);
            rr += __shfl_down(rr, 1);
            if (cl == 0) out[(size_t)sidx[i16 + q + 4 * j] * 2 + 1] = rr;
        }
    }

    short8 pvA[3][2];
#pragma unroll
    for (int k = 0; k < 3; ++k) {
#pragma unroll
        for (int t = 0; t < 4; ++t)
#pragma unroll
            for (int r = 0; r < 4; ++r)
                xls[(q * 4 + r) * 65 + t * 16 + cl] = pvsD[t][r] * vD[k][t][r];
#pragma unroll
        for (int h = 0; h < 2; ++h) {
            const float* rp = xls + cl * 65 + h * 32 + q * 8;
            float t0 = rp[0], t1 = rp[1], t2 = rp[2], t3 = rp[3];
            float t4 = rp[4], t5 = rp[5], t6 = rp[6], t7 = rp[7];
            pvA[k][h] = cvt8(make_float4(t0, t1, t2, t3), make_float4(t4, t5, t6, t7));
        }
    }

    f32x4 vnD[3][4];
#pragma unroll
    for (int k = 0; k < 3; ++k)
#pragma unroll
        for (int t = 0; t < 4; ++t) vnD[k][t] = (f32x4){0.f, 0.f, 0.f, 0.f};
#pragma unroll
    for (int t = 0; t < 4; ++t)
#pragma unroll
        for (int h = 0; h < 2; ++h) {
            short8 b = loadB(pWpv, t, h, l);
#pragma unroll
            for (int k = 0; k < 3; ++k) vnD[k][t] = MFMA16(pvA[k][h], b, vnD[k][t]);
        }
    if (has_skip) {
        short8 Aiv[3][2];
#pragma unroll
        for (int k = 0; k < 3; ++k) {
            const unsigned short* r = v + ((size_t)(i16 + cl) * 3 + k) * 64;
            Aiv[k][0] = *(const short8*)(r + q * 8);
            Aiv[k][1] = *(const short8*)(r + 32 + q * 8);
        }
        int myz = spec_srt[i16 + cl];
        for (int z = z0; z <= z1; ++z) {
            bool keep = (myz == z);
            const short* pz = pSkV + (size_t)z * 4096;
#pragma unroll
            for (int t = 0; t < 4; ++t)
#pragma unroll
                for (int h = 0; h < 2; ++h) {
                    short8 b = loadB(pz, t, h, l);
#pragma unroll
                    for (int k = 0; k < 3; ++k) {
                        short8 a = keep ? Aiv[k][h] : z8;
                        vnD[k][t] = MFMA16(a, b, vnD[k][t]);
                    }
                }
        }
    }
#pragma unroll
    for (int k = 0; k < 3; ++k)
#pragma unroll
        for (int t = 0; t < 4; ++t)
#pragma unroll
            for (int r = 0; r < 4; ++r)
                v[((size_t)(i16 + q * 4 + r) * 3 + k) * 64 + t * 16 + cl] = f2bf(vnD[k][t][r]);

    // ---- it==0: zero this wave's own agg boundary rows for interaction 1.
    if (it == 0) {
        for (int rr = 0; rr < 16; ++rr) {
            int i = i16 + rr;
            int beg = row_start[i], end = row_start[i + 1];
            bool need = (end == beg) || (end > (((beg >> 4) + 1) << 4));
            if (need) {
                float* as = (float*)agg_s;
                float* av = (float*)agg_v;
                as[(size_t)i * 64 + l] = 0.f;
                av[((size_t)i * 3 + 0) * 64 + l] = 0.f;
                av[((size_t)i * 3 + 1) * 64 + l] = 0.f;
                av[((size_t)i * 3 + 2) * 64 + l] = 0.f;
            }
        }
    }
}

// ---------------------------------------------------------------------------
extern "C" void kernel_launch(void* const* d_in, const int* in_sizes, int n_in,
                              void* d_out, int out_size, void* d_ws, size_t ws_size,
                              hipStream_t stream)
{
    const float* vectors = (const float*)d_in[0];
    const float* embed_s = (const float*)d_in[1];
    const float* Wr      = (const float*)d_in[2];   // [2,8,320]
    const float* Wls     = (const float*)d_in[3];   // [2,64,64]
    const float* Wlv     = (const float*)d_in[4];
    const float* skip_s  = (const float*)d_in[5];   // [10,64,64]
    const float* skip_v  = (const float*)d_in[6];
    const float* pw      = (const float*)d_in[7];   // [2,10,9,64]
    const float* Wps     = (const float*)d_in[8];
    const float* Wpv     = (const float*)d_in[9];
    const float* Wread0  = (const float*)d_in[10];  // [64,1]
    const float* Wr1a    = (const float*)d_in[11];  // [64,16]
    const float* Wr1b    = (const float*)d_in[12];  // [16,1]
    const int* senders   = (const int*)d_in[13];
    const int* receivers = (const int*)d_in[14];
    const int* species   = (const int*)d_in[15];
    float* out = (float*)d_out;

    float* ws = (float*)d_ws;
    float* edata = ws; ws += (size_t)N_EDGES * 16;  // 16 MB (slot-ordered)
    float* agg_s = ws; ws += (size_t)N_NODES * 64;  // 8 MB
    float* agg_v = ws; ws += (size_t)N_NODES * 192; // 24 MB
    unsigned short* s = (unsigned short*)ws; ws += (size_t)N_NODES * 32;  // 4 MB bf16
    unsigned short* v = (unsigned short*)ws; ws += (size_t)N_NODES * 96;  // 12 MB bf16
    int* counts    = (int*)ws; ws += N_NODES;
    int* row_start = (int*)ws; ws += N_NODES + 4;
    int* cursor    = (int*)ws; ws += N_NODES;
    int* edge_ids  = (int*)ws; ws += N_EDGES;
    int* srk       = (int*)ws; ws += N_EDGES;
    int* grp_row   = (int*)ws; ws += N_EDGES / 16;
    int* sidx      = (int*)ws; ws += N_NODES;
    int* rank      = (int*)ws; ws += N_NODES;
    int* spec_srt  = (int*)ws; ws += N_NODES;
    int* lrank_arr = (int*)ws; ws += N_NODES;
    int* counts_blk = (int*)ws; ws += 128 * NSPEC;
    int* off_blk    = (int*)ws; ws += 128 * NSPEC;
    short* packW   = (short*)ws;                    // 224 KB

    // species counting sort (sort1 also zeroes CSR counts)
    sort1_kernel<<<N_NODES / 256, 256, 0, stream>>>(
        species, counts_blk, lrank_arr, counts);
    sort2_kernel<<<1, 640, 0, stream>>>(counts_blk, off_blk);
    sort3_kernel<<<N_NODES / 256, 256, 0, stream>>>(
        species, lrank_arr, off_blk, sidx, rank, spec_srt);

    // receiver CSR in sorted space
    hist_kernel<<<N_EDGES / 256, 256, 0, stream>>>(receivers, rank, counts);
    scan_kernel<<<1, 1024, 0, stream>>>(counts, row_start, cursor);
    scatter_kernel<<<N_EDGES / 256, 256, 0, stream>>>(receivers, rank, cursor, edge_ids);

    // edge features + packed sender rank/species + grp_row (one pass)
    edge_pre_kernel<<<N_EDGES / 256, 256, 0, stream>>>(
        vectors, edge_ids, senders, rank, species, row_start, edata, srk, grp_row);

    // merged prep: weight pack + zero boundary agg rows (i0). No init_s.
    prep_kernel<<<2048, 256, 0, stream>>>(
        Wls, Wlv, Wps, Wpv, skip_s, skip_v, packW, row_start, agg_s, agg_v);

    // interaction 0 (gather reads embed table; node fuses read0 + re-zeroing)
    gather_kernel<1><<<N_EDGES / 128, 256, 0, stream>>>(
        edata, srk, row_start, grp_row, embed_s, s, v, Wr, agg_s, agg_v);
    node_mfma_kernel<<<N_NODES / 64, 256, 0, stream>>>(
        agg_s, agg_v, s, v, packW, 0, pw, spec_srt,
        row_start, sidx, Wread0, Wr1a, Wr1b, out, 0);

    // interaction 1 (bf16 s/v state halves random gather traffic)
    gather_kernel<0><<<N_EDGES / 128, 256, 0, stream>>>(
        edata, srk, row_start, grp_row, embed_s, s, v, Wr + 2560, agg_s, agg_v);
    node_mfma_kernel<<<N_NODES / 64, 256, 0, stream>>>(
        agg_s, agg_v, s, v, packW, 1, pw + 5760, spec_srt,
        row_start, sidx, Wread0, Wr1a, Wr1b, out, 1);
}

// Round 2
// 288.603 us; speedup vs baseline: 1.1007x; 1.1007x over previous
//
#include <hip/hip_runtime.h>
#include <hip/hip_bf16.h>
#include <math.h>

#define N_NODES 32768
#define N_EDGES 262144
#define EPS_C 0.24253562503633297f   // 1/sqrt(17)
#define NSPEC 10

typedef __attribute__((ext_vector_type(8))) short short8;   // 8 bf16
typedef __attribute__((ext_vector_type(4))) float f32x4;    // 4 fp32 acc

#define MFMA16(a, b, c) __builtin_amdgcn_mfma_f32_16x16x32_bf16(a, b, c, 0, 0, 0)

__device__ __forceinline__ short2 cvt2(float a, float b) {
    union { __hip_bfloat162 h; short2 s; } u;
    u.h = __float22bfloat162_rn(make_float2(a, b));
    return u.s;
}
__device__ __forceinline__ unsigned short f2bf(float a) {
    return (unsigned short)cvt2(a, 0.f).x;
}
__device__ __forceinline__ float bf2f(unsigned short u) {
    return __uint_as_float(((unsigned)u) << 16);
}
__device__ __forceinline__ short8 cvt8(float4 a, float4 b) {
    short2 p0 = cvt2(a.x, a.y), p1 = cvt2(a.z, a.w);
    short2 p2 = cvt2(b.x, b.y), p3 = cvt2(b.z, b.w);
    short8 r;
    r[0] = p0.x; r[1] = p0.y; r[2] = p1.x; r[3] = p1.y;
    r[4] = p2.x; r[5] = p2.y; r[6] = p3.x; r[7] = p3.y;
    return r;
}
__device__ __forceinline__ short8 loadArow(const float* rowp, int h, int q) {
    const float* p = rowp + h * 32 + q * 8;
    return cvt8(*(const float4*)p, *(const float4*)(p + 4));
}
__device__ __forceinline__ short8 loadB(const short* P, int t, int h, int l) {
    return *(const short8*)(P + (((t * 2 + h) * 64 + l) << 3));
}

// ---------------------------------------------------------------------------
// Species counting sort — contention-free, deterministic. sort1 also zeroes
// the receiver-CSR counts array.
// ---------------------------------------------------------------------------
__global__ __launch_bounds__(256) void sort1_kernel(
    const int* __restrict__ species, int* __restrict__ counts_blk,
    int* __restrict__ lrank_arr, int* __restrict__ counts)
{
    __shared__ int wcnt[4][16];
    int n = blockIdx.x * 256 + threadIdx.x;
    counts[n] = 0;
    int sp = species[n];
    int lane = threadIdx.x & 63, wv = threadIdx.x >> 6;
    unsigned long long ltmask = (1ull << lane) - 1;
    int lrank_w = 0;
#pragma unroll
    for (int z = 0; z < NSPEC; ++z) {
        unsigned long long m = __ballot(sp == z);
        if (sp == z) lrank_w = __popcll(m & ltmask);
        if (lane == 0) wcnt[wv][z] = __popcll(m);
    }
    __syncthreads();
    int off = 0;
    for (int w = 0; w < wv; ++w) off += wcnt[w][sp];
    lrank_arr[n] = lrank_w + off;
    if (threadIdx.x < NSPEC)
        counts_blk[blockIdx.x * NSPEC + threadIdx.x] =
            wcnt[0][threadIdx.x] + wcnt[1][threadIdx.x] +
            wcnt[2][threadIdx.x] + wcnt[3][threadIdx.x];
}

// parallel block-offset scan: wave z shuffle-scans its 128 block counts
__global__ __launch_bounds__(640) void sort2_kernel(
    const int* __restrict__ counts_blk, int* __restrict__ off_blk)
{
    __shared__ int totals[16];
    int wv = threadIdx.x >> 6;        // 0..9 == species z
    int lane = threadIdx.x & 63;
    int c0 = counts_blk[lane * NSPEC + wv];
    int c1 = counts_blk[(64 + lane) * NSPEC + wv];
    int s0 = c0;
#pragma unroll
    for (int off = 1; off < 64; off <<= 1) {
        int y = __shfl_up(s0, off);
        if (lane >= off) s0 += y;
    }
    int tot0 = __shfl(s0, 63);
    int s1 = c1;
#pragma unroll
    for (int off = 1; off < 64; off <<= 1) {
        int y = __shfl_up(s1, off);
        if (lane >= off) s1 += y;
    }
    s1 += tot0;
    if (lane == 63) totals[wv] = s1;
    __syncthreads();
    int base = 0;
    for (int q = 0; q < wv; ++q) base += totals[q];
    off_blk[lane * NSPEC + wv] = base + s0 - c0;
    off_blk[(64 + lane) * NSPEC + wv] = base + s1 - c1;
}

__global__ __launch_bounds__(256) void sort3_kernel(
    const int* __restrict__ species, const int* __restrict__ lrank_arr,
    const int* __restrict__ off_blk,
    int* __restrict__ sidx, int* __restrict__ rank, int* __restrict__ spec_srt)
{
    int n = blockIdx.x * 256 + threadIdx.x;
    int sp = species[n];
    int slot = off_blk[blockIdx.x * NSPEC + sp] + lrank_arr[n];
    sidx[slot] = n;
    rank[n] = slot;
    spec_srt[slot] = sp;
}

// ---------------------------------------------------------------------------
// Receiver CSR in SORTED space
// ---------------------------------------------------------------------------
__global__ __launch_bounds__(256) void hist_kernel(
    const int* __restrict__ receivers, const int* __restrict__ rank,
    int* __restrict__ counts)
{
    int e = blockIdx.x * 256 + threadIdx.x;
    atomicAdd(&counts[rank[receivers[e]]], 1);
}

__global__ __launch_bounds__(1024) void scan_kernel(
    const int* __restrict__ counts, int* __restrict__ row_start, int* __restrict__ cursor)
{
    __shared__ int wave_tot[16];
    int tid = threadIdx.x;
    int c[32];
    int sum = 0;
#pragma unroll
    for (int i = 0; i < 32; ++i) { c[i] = counts[tid * 32 + i]; sum += c[i]; }
    int lane = tid & 63, wv = tid >> 6;
    int x = sum;
#pragma unroll
    for (int off = 1; off < 64; off <<= 1) {
        int y = __shfl_up(x, off);
        if (lane >= off) x += y;
    }
    if (lane == 63) wave_tot[wv] = x;
    __syncthreads();
    if (wv == 0 && lane < 16) {
        int t = wave_tot[lane];
#pragma unroll
        for (int off = 1; off < 16; off <<= 1) {
            int y = __shfl_up(t, off);
            if (lane >= off) t += y;
        }
        wave_tot[lane] = t;
    }
    __syncthreads();
    int excl = x - sum + (wv ? wave_tot[wv - 1] : 0);
    int run = excl;
#pragma unroll
    for (int i = 0; i < 32; ++i) {
        row_start[tid * 32 + i] = run;
        cursor[tid * 32 + i] = run;
        run += c[i];
    }
    if (tid == 1023) row_start[32768] = run;
}

__global__ __launch_bounds__(256) void scatter_kernel(
    const int* __restrict__ receivers, const int* __restrict__ rank,
    int* __restrict__ cursor, int* __restrict__ edge_ids)
{
    int e = blockIdx.x * 256 + threadIdx.x;
    int slot = atomicAdd(&cursor[rank[receivers[e]]], 1);
    edge_ids[slot] = e;
}

// ---------------------------------------------------------------------------
// Edge precompute in slot order + fused sender-rank/species stream + grp_row.
// srk[p] = rank | (species << 16)
// ---------------------------------------------------------------------------
__global__ __launch_bounds__(256) void edge_pre_kernel(
    const float* __restrict__ vectors, const int* __restrict__ edge_ids,
    const int* __restrict__ senders, const int* __restrict__ rank,
    const int* __restrict__ species, const int* __restrict__ row_start,
    float* __restrict__ edata, int* __restrict__ srk, int* __restrict__ grp_row)
{
    int p = blockIdx.x * 256 + threadIdx.x;
    int e = edge_ids[p];
    int snd = senders[e];
    srk[p] = rank[snd] | (species[snd] << 16);
    float x = vectors[e * 3 + 0], y = vectors[e * 3 + 1], z = vectors[e * 3 + 2];
    float r2 = x * x + y * y + z * z + 1e-12f;
    float r = sqrtf(r2);
    float inv = 1.0f / r;
    float* d = edata + (size_t)p * 16;
    *(float4*)d = make_float4(x * inv, y * inv, z * inv, 0.0f);
    float rc = fmaxf(r, 1e-6f);
    float r6 = r2 * r2 * r2;
    float r7 = r6 * r;
    float r8 = r6 * r2;
    float env = (r < 1.0f) ? (1.0f - 28.0f * r6 + 48.0f * r7 - 21.0f * r8) : 0.0f;
    float sc = 1.41421356237309515f * env / rc;
#pragma unroll
    for (int j = 0; j < 8; ++j)
        d[4 + j] = sc * sinf((float)(j + 1) * 3.14159265358979323846f * rc);
    d[12] = 0.f; d[13] = 0.f; d[14] = 0.f; d[15] = 0.f;

    if (p < N_EDGES / 16) {
        int target = p * 16;
        int lo = 0, hi = N_NODES - 1;
        while (lo < hi) {
            int mid = (lo + hi + 1) >> 1;
            if (row_start[mid] <= target) lo = mid; else hi = mid - 1;
        }
        grp_row[p] = lo;
    }
}

// ---------------------------------------------------------------------------
// Merged prep: weight pack (blocks<448) + zero_bnd for interaction 0.
// ---------------------------------------------------------------------------
__global__ __launch_bounds__(256) void prep_kernel(
    const float* __restrict__ Wls, const float* __restrict__ Wlv,
    const float* __restrict__ Wps, const float* __restrict__ Wpv,
    const float* __restrict__ skip_s, const float* __restrict__ skip_v,
    short* __restrict__ packW,
    const int* __restrict__ row_start,
    float* __restrict__ agg_s, float* __restrict__ agg_v)
{
    int idx = blockIdx.x * 256 + threadIdx.x;
    if (blockIdx.x < 448 && idx < 28 * 4096) {
        int m = idx >> 12, e = idx & 4095;
        int t = e >> 10, h = (e >> 9) & 1, l = (e >> 3) & 63, j = e & 7;
        int fi = h * 32 + ((l >> 4) << 3) + j;
        int fo = t * 16 + (l & 15);
        const float* src;
        if      (m < 2)  src = Wls    + m * 4096;
        else if (m < 4)  src = Wlv    + (m - 2) * 4096;
        else if (m < 6)  src = Wps    + (m - 4) * 4096;
        else if (m < 8)  src = Wpv    + (m - 6) * 4096;
        else if (m < 18) src = skip_s + (m - 8) * 4096;
        else             src = skip_v + (m - 18) * 4096;
        packW[idx] = cvt2(src[fi * 64 + fo], 0.f).x;
    }
    const int wid = threadIdx.x >> 6;
    const int f = threadIdx.x & 63;
    const int base = (blockIdx.x * 4 + wid) * 4;
#pragma unroll
    for (int t = 0; t < 4; ++t) {
        int i = base + t;
        int beg = row_start[i], end = row_start[i + 1];
        bool need = (end == beg) || (end > (((beg >> 4) + 1) << 4));
        if (need) {
            agg_s[(size_t)i * 64 + f] = 0.f;
            agg_v[((size_t)i * 3 + 0) * 64 + f] = 0.f;
            agg_v[((size_t)i * 3 + 1) * 64 + f] = 0.f;
            agg_v[((size_t)i * 3 + 2) * 64 + f] = 0.f;
        }
    }
}

// ---------------------------------------------------------------------------
// Dual-chain edge-balanced gather, 1 wave/block (round-0 config), now with a
// TRUE depth-2 software pipeline: raw bf16 bits are staged in registers and
// converted only at consume time, so the vmcnt wait lands two iterations
// after issue. The 16-iter loop is fully unrolled so stage rotation becomes
// SSA renames (a rolled loop would force a waitcnt at the v_mov rotation).
// srk is prefetched at distance 3 with a clamped index, so every staged
// entry is a real rank|species word and all speculative loads stay in-bounds.
// VZERO: s from 2.5KB embed table (L1-resident; pipeline depth irrelevant).
// ---------------------------------------------------------------------------
template<int VZERO>
__global__ __launch_bounds__(64, 4) void gather_kernel(
    const float* __restrict__ edata, const int* __restrict__ srk,
    const int* __restrict__ row_start, const int* __restrict__ grp_row,
    const float* __restrict__ embed_s,
    const unsigned short* __restrict__ s_in, const unsigned short* __restrict__ v_in,
    const float* __restrict__ Wr_i,
    float* __restrict__ agg_s, float* __restrict__ agg_v)
{
    const int f = threadIdx.x & 63;
    const int w = blockIdx.x;
    const int pA0 = w * 32;
    const int pB0 = pA0 + 16;

    float wr[5][8];
#pragma unroll
    for (int j = 0; j < 8; ++j)
#pragma unroll
        for (int p = 0; p < 5; ++p)
            wr[p][j] = (VZERO && (p == 1 || p == 3 || p == 4))
                       ? 0.f : Wr_i[j * 320 + p * 64 + f];

    int rA = grp_row[2 * w], rB = grp_row[2 * w + 1];
    int begA = row_start[rA], endA = row_start[rA + 1];
    int begB = row_start[rB], endB = row_start[rB + 1];
    float aA0 = 0.f, aA1 = 0.f, aA2 = 0.f, aA3 = 0.f;
    float aB0 = 0.f, aB1 = 0.f, aB2 = 0.f, aB3 = 0.f;

    // 3-stage pipeline state. Stage0 = edge k (consumed this iter),
    // stage1 = edge k+1 (in flight), stage2 = edge k+2 (issued this iter).
    int svA2 = srk[pA0 + 2], svB2 = srk[pB0 + 2];
    unsigned short sA0r = 0, sB0r = 0, sA1r = 0, sB1r = 0;
    float sA0f = 0.f, sB0f = 0.f, sA1f = 0.f, sB1f = 0.f;
    unsigned short vA0r0 = 0, vA0r1 = 0, vA0r2 = 0, vB0r0 = 0, vB0r1 = 0, vB0r2 = 0;
    unsigned short vA1r0 = 0, vA1r1 = 0, vA1r2 = 0, vB1r0 = 0, vB1r1 = 0, vB1r2 = 0;
    {
        int svA0 = srk[pA0], svB0 = srk[pB0];
        int svA1 = srk[pA0 + 1], svB1 = srk[pB0 + 1];
        if (VZERO) {
            sA0f = embed_s[(svA0 >> 16) * 64 + f];
            sB0f = embed_s[(svB0 >> 16) * 64 + f];
            sA1f = embed_s[(svA1 >> 16) * 64 + f];
            sB1f = embed_s[(svB1 >> 16) * 64 + f];
        } else {
            int a0 = svA0 & 0xFFFF, b0 = svB0 & 0xFFFF;
            int a1 = svA1 & 0xFFFF, b1 = svB1 & 0xFFFF;
            sA0r = s_in[(size_t)a0 * 64 + f];
            sB0r = s_in[(size_t)b0 * 64 + f];
            sA1r = s_in[(size_t)a1 * 64 + f];
            sB1r = s_in[(size_t)b1 * 64 + f];
            vA0r0 = v_in[((size_t)a0 * 3 + 0) * 64 + f];
            vA0r1 = v_in[((size_t)a0 * 3 + 1) * 64 + f];
            vA0r2 = v_in[((size_t)a0 * 3 + 2) * 64 + f];
            vB0r0 = v_in[((size_t)b0 * 3 + 0) * 64 + f];
            vB0r1 = v_in[((size_t)b0 * 3 + 1) * 64 + f];
            vB0r2 = v_in[((size_t)b0 * 3 + 2) * 64 + f];
            vA1r0 = v_in[((size_t)a1 * 3 + 0) * 64 + f];
            vA1r1 = v_in[((size_t)a1 * 3 + 1) * 64 + f];
            vA1r2 = v_in[((size_t)a1 * 3 + 2) * 64 + f];
            vB1r0 = v_in[((size_t)b1 * 3 + 0) * 64 + f];
            vB1r1 = v_in[((size_t)b1 * 3 + 1) * 64 + f];
            vB1r2 = v_in[((size_t)b1 * 3 + 2) * 64 + f];
        }
    }

#pragma unroll
    for (int k = 0; k < 16; ++k) {
        const int pA = pA0 + k, pB = pB0 + k;
        // srk prefetch for edge k+3 (A side is always in-bounds: pA0+18 fits;
        // B side clamps to the last valid entry so the value stays well-formed)
        int svA3 = srk[pA + 3];
        int iB3 = pB + 3;
        int svB3 = srk[iB3 < N_EDGES ? iB3 : N_EDGES - 1];

        // issue stage-2 state loads (edge k+2) — raw bits, no conversion here
        unsigned short sA2r = 0, sB2r = 0;
        float sA2f = 0.f, sB2f = 0.f;
        unsigned short vA2r0 = 0, vA2r1 = 0, vA2r2 = 0;
        unsigned short vB2r0 = 0, vB2r1 = 0, vB2r2 = 0;
        if (VZERO) {
            sA2f = embed_s[(svA2 >> 16) * 64 + f];
            sB2f = embed_s[(svB2 >> 16) * 64 + f];
        } else {
            int a2 = svA2 & 0xFFFF, b2 = svB2 & 0xFFFF;
            sA2r = s_in[(size_t)a2 * 64 + f];
            sB2r = s_in[(size_t)b2 * 64 + f];
            vA2r0 = v_in[((size_t)a2 * 3 + 0) * 64 + f];
            vA2r1 = v_in[((size_t)a2 * 3 + 1) * 64 + f];
            vA2r2 = v_in[((size_t)a2 * 3 + 2) * 64 + f];
            vB2r0 = v_in[((size_t)b2 * 3 + 0) * 64 + f];
            vB2r1 = v_in[((size_t)b2 * 3 + 1) * 64 + f];
            vB2r2 = v_in[((size_t)b2 * 3 + 2) * 64 + f];
        }

        const float* dA = edata + (size_t)pA * 16;
        const float* dB = edata + (size_t)pB * 16;
        float4 yA = *(const float4*)dA;
        float4 qA0 = *(const float4*)(dA + 4);
        float4 qA1 = *(const float4*)(dA + 8);
        float4 yB = *(const float4*)dB;
        float4 qB0 = *(const float4*)(dB + 4);
        float4 qB1 = *(const float4*)(dB + 8);

        float rbA[8] = {qA0.x, qA0.y, qA0.z, qA0.w, qA1.x, qA1.y, qA1.z, qA1.w};
        float rbB[8] = {qB0.x, qB0.y, qB0.z, qB0.w, qB1.x, qB1.y, qB1.z, qB1.w};
        float wA0 = 0.f, wA1 = 0.f, wA2 = 0.f, wA3 = 0.f, wA4 = 0.f;
        float wB0 = 0.f, wB1 = 0.f, wB2 = 0.f, wB3 = 0.f, wB4 = 0.f;
#pragma unroll
        for (int j = 0; j < 8; ++j) {
            wA0 = fmaf(rbA[j], wr[0][j], wA0);  wB0 = fmaf(rbB[j], wr[0][j], wB0);
            if (!VZERO) { wA1 = fmaf(rbA[j], wr[1][j], wA1);  wB1 = fmaf(rbB[j], wr[1][j], wB1); }
            wA2 = fmaf(rbA[j], wr[2][j], wA2);  wB2 = fmaf(rbB[j], wr[2][j], wB2);
            if (!VZERO) { wA3 = fmaf(rbA[j], wr[3][j], wA3);  wB3 = fmaf(rbB[j], wr[3][j], wB3); }
            if (!VZERO) { wA4 = fmaf(rbA[j], wr[4][j], wA4);  wB4 = fmaf(rbB[j], wr[4][j], wB4); }
        }

        // consume stage0 — conversion (exact shift) happens HERE, so the
        // s_waitcnt for these loads lands 2 iterations after issue.
        if (VZERO) {
            float ssA = sA0f, ssB = sB0f;
            aA0 += wA0 * ssA;
            float wsA = wA2 * ssA;
            aA1 += wsA * yA.x; aA2 += wsA * yA.y; aA3 += wsA * yA.z;
            aB0 += wB0 * ssB;
            float wsB = wB2 * ssB;
            aB1 += wsB * yB.x; aB2 += wsB * yB.y; aB3 += wsB * yB.z;
        } else {
            float ssA = bf2f(sA0r), ssB = bf2f(sB0r);
            float va0 = bf2f(vA0r0), va1 = bf2f(vA0r1), va2 = bf2f(vA0r2);
            float vb0 = bf2f(vB0r0), vb1 = bf2f(vB0r1), vb2 = bf2f(vB0r2);
            float dotA = va0 * yA.x + va1 * yA.y + va2 * yA.z;
            aA0 += wA0 * ssA + wA1 * dotA;
            float cA0 = va1 * yA.z - va2 * yA.y;
            float cA1 = va2 * yA.x - va0 * yA.z;
            float cA2 = va0 * yA.y - va1 * yA.x;
            float wsA = wA2 * ssA;
            aA1 += wsA * yA.x + wA3 * va0 + wA4 * cA0;
            aA2 += wsA * yA.y + wA3 * va1 + wA4 * cA1;
            aA3 += wsA * yA.z + wA3 * va2 + wA4 * cA2;
            float dotB = vb0 * yB.x + vb1 * yB.y + vb2 * yB.z;
            aB0 += wB0 * ssB + wB1 * dotB;
            float cB0 = vb1 * yB.z - vb2 * yB.y;
            float cB1 = vb2 * yB.x - vb0 * yB.z;
            float cB2 = vb0 * yB.y - vb1 * yB.x;
            float wsB = wB2 * ssB;
            aB1 += wsB * yB.x + wB3 * vb0 + wB4 * cB0;
            aB2 += wsB * yB.y + wB3 * vb1 + wB4 * cB1;
            aB3 += wsB * yB.z + wB3 * vb2 + wB4 * cB2;
        }

        if (pA + 1 == endA || k == 15) {
            bool interior = (begA >= pA0) && (endA <= pA0 + 16);
            if (interior) {
                agg_s[(size_t)rA * 64 + f] = aA0;
                agg_v[((size_t)rA * 3 + 0) * 64 + f] = aA1;
                agg_v[((size_t)rA * 3 + 1) * 64 + f] = aA2;
                agg_v[((size_t)rA * 3 + 2) * 64 + f] = aA3;
            } else {
                unsafeAtomicAdd(&agg_s[(size_t)rA * 64 + f], aA0);
                unsafeAtomicAdd(&agg_v[((size_t)rA * 3 + 0) * 64 + f], aA1);
                unsafeAtomicAdd(&agg_v[((size_t)rA * 3 + 1) * 64 + f], aA2);
                unsafeAtomicAdd(&agg_v[((size_t)rA * 3 + 2) * 64 + f], aA3);
            }
            aA0 = aA1 = aA2 = aA3 = 0.f;
            if (pA + 1 == endA && k < 15) {
                begA = endA; ++rA; endA = row_start[rA + 1];
                while (endA == begA) { ++rA; endA = row_start[rA + 1]; }
            }
        }
        if (pB + 1 == endB || k == 15) {
            bool interior = (begB >= pB0) && (endB <= pB0 + 16);
            if (interior) {
                agg_s[(size_t)rB * 64 + f] = aB0;
                agg_v[((size_t)rB * 3 + 0) * 64 + f] = aB1;
                agg_v[((size_t)rB * 3 + 1) * 64 + f] = aB2;
                agg_v[((size_t)rB * 3 + 2) * 64 + f] = aB3;
            } else {
                unsafeAtomicAdd(&agg_s[(size_t)rB * 64 + f], aB0);
                unsafeAtomicAdd(&agg_v[((size_t)rB * 3 + 0) * 64 + f], aB1);
                unsafeAtomicAdd(&agg_v[((size_t)rB * 3 + 1) * 64 + f], aB2);
                unsafeAtomicAdd(&agg_v[((size_t)rB * 3 + 2) * 64 + f], aB3);
            }
            aB0 = aB1 = aB2 = aB3 = 0.f;
            if (pB + 1 == endB && k < 15) {
                begB = endB; ++rB; endB = row_start[rB + 1];
                while (endB == begB) { ++rB; endB = row_start[rB + 1]; }
            }
        }

        // rotate stages (SSA renames under full unroll — no movs, no waits)
        sA0r = sA1r; sB0r = sB1r; sA1r = sA2r; sB1r = sB2r;
        sA0f = sA1f; sB0f = sB1f; sA1f = sA2f; sB1f = sB2f;
        vA0r0 = vA1r0; vA0r1 = vA1r1; vA0r2 = vA1r2;
        vB0r0 = vB1r0; vB0r1 = vB1r1; vB0r2 = vB1r2;
        vA1r0 = vA2r0; vA1r1 = vA2r1; vA1r2 = vA2r2;
        vB1r0 = vB2r0; vB1r1 = vB2r1; vB1r2 = vB2r2;
        svA2 = svA3; svB2 = svB3;
    }
}

// ---------------------------------------------------------------------------
// MFMA node kernel, bf16 s/v state: skip A-fragments are direct short8 loads
// (bit-exact vs fp32 path); s/v stores are RNE-bf16. Fused readout uses
// pre-rounded fp32 registers. wave = 16 sorted nodes.
// ---------------------------------------------------------------------------
__global__ __launch_bounds__(256) void node_mfma_kernel(
    const float* __restrict__ agg_s, const float* __restrict__ agg_v,
    unsigned short* s, unsigned short* v,
    const short* __restrict__ packW, int it,
    const float* __restrict__ pw_i,
    const int* __restrict__ spec_srt,
    const int* __restrict__ row_start, const int* __restrict__ sidx,
    const float* __restrict__ Wread0, const float* __restrict__ Wr1a,
    const float* __restrict__ Wr1b,
    float* __restrict__ out,
    int has_skip)
{
    const int l = threadIdx.x & 63;
    const int wid = threadIdx.x >> 6;
    const int cl = l & 15;
    const int q = l >> 4;
    const int i16 = (blockIdx.x * 4 + wid) * 16;
    __shared__ float xls_all[4][16 * 65];
    float* xls = xls_all[wid];

    const short* pWls = packW + (size_t)(0 + it) * 4096;
    const short* pWlv = packW + (size_t)(2 + it) * 4096;
    const short* pWps = packW + (size_t)(4 + it) * 4096;
    const short* pWpv = packW + (size_t)(6 + it) * 4096;
    const short* pSkS = packW + (size_t)8 * 4096;
    const short* pSkV = packW + (size_t)18 * 4096;
    const short8 z8 = {0, 0, 0, 0, 0, 0, 0, 0};

    const float* ars = agg_s + (size_t)(i16 + cl) * 64;
    short8 As[2] = { loadArow(ars, 0, q), loadArow(ars, 1, q) };
    short8 Av[3][2];
#pragma unroll
    for (int k = 0; k < 3; ++k) {
        const float* r = agg_v + ((size_t)(i16 + cl) * 3 + k) * 64;
        Av[k][0] = loadArow(r, 0, q);
        Av[k][1] = loadArow(r, 1, q);
    }

    f32x4 sD[4];
#pragma unroll
    for (int t = 0; t < 4; ++t) {
        f32x4 acc = {0.f, 0.f, 0.f, 0.f};
        acc = MFMA16(As[0], loadB(pWls, t, 0, l), acc);
        acc = MFMA16(As[1], loadB(pWls, t, 1, l), acc);
        sD[t] = acc;
    }

    f32x4 vD[3][4];
#pragma unroll
    for (int k = 0; k < 3; ++k)
#pragma unroll
        for (int t = 0; t < 4; ++t) vD[k][t] = (f32x4){0.f, 0.f, 0.f, 0.f};
#pragma unroll
    for (int t = 0; t < 4; ++t)
#pragma unroll
        for (int h = 0; h < 2; ++h) {
            short8 b = loadB(pWlv, t, h, l);
#pragma unroll
            for (int k = 0; k < 3; ++k) vD[k][t] = MFMA16(Av[k][h], b, vD[k][t]);
        }

    int z0 = spec_srt[i16], z1 = spec_srt[i16 + 15];
    float psD[4][4], pvsD[4][4];
    if (z0 == z1) {
        const float* pb = pw_i + z0 * 576 + cl;
        float pc[9][4];
#pragma unroll
        for (int c = 0; c < 9; ++c)
#pragma unroll
            for (int t = 0; t < 4; ++t) pc[c][t] = pb[c * 64 + t * 16];
#pragma unroll
        for (int t = 0; t < 4; ++t)
#pragma unroll
            for (int r = 0; r < 4; ++r) {
                float x = sD[t][r] * EPS_C;
                float w0 = vD[0][t][r] * EPS_C;
                float w1 = vD[1][t][r] * EPS_C;
                float w2 = vD[2][t][r] * EPS_C;
                vD[0][t][r] = w0; vD[1][t][r] = w1; vD[2][t][r] = w2;
                float vv = w0 * w0 + w1 * w1 + w2 * w2;
                float x2 = x * x;
                psD[t][r] = pc[0][t] * x + pc[1][t] * x2 + pc[2][t] * vv
                          + pc[3][t] * x2 * x + pc[4][t] * x * vv;
                pvsD[t][r] = pc[5][t] + pc[6][t] * x + pc[7][t] * x2 + pc[8][t] * vv;
            }
    } else {
#pragma unroll
        for (int r = 0; r < 4; ++r) {
            int z = spec_srt[i16 + q * 4 + r];
            const float* pb = pw_i + z * 576 + cl;
#pragma unroll
            for (int t = 0; t < 4; ++t) {
                float p0 = pb[t*16], p1 = pb[64+t*16], p2 = pb[128+t*16];
                float p3 = pb[192+t*16], p4 = pb[256+t*16], p5 = pb[320+t*16];
                float p6 = pb[384+t*16], p7 = pb[448+t*16], p8 = pb[512+t*16];
                float x = sD[t][r] * EPS_C;
                float w0 = vD[0][t][r] * EPS_C;
                float w1 = vD[1][t][r] * EPS_C;
                float w2 = vD[2][t][r] * EPS_C;
                vD[0][t][r] = w0; vD[1][t][r] = w1; vD[2][t][r] = w2;
                float vv = w0 * w0 + w1 * w1 + w2 * w2;
                float x2 = x * x;
                psD[t][r] = p0 * x + p1 * x2 + p2 * vv + p3 * x2 * x + p4 * x * vv;
                pvsD[t][r] = p5 + p6 * x + p7 * x2 + p8 * vv;
            }
        }
    }

#pragma unroll
    for (int t = 0; t < 4; ++t)
#pragma unroll
        for (int r = 0; r < 4; ++r)
            xls[(q * 4 + r) * 65 + t * 16 + cl] = psD[t][r];
    short8 psA[2];
#pragma unroll
    for (int h = 0; h < 2; ++h) {
        const float* rp = xls + cl * 65 + h * 32 + q * 8;
        float t0 = rp[0], t1 = rp[1], t2 = rp[2], t3 = rp[3];
        float t4 = rp[4], t5 = rp[5], t6 = rp[6], t7 = rp[7];
        psA[h] = cvt8(make_float4(t0, t1, t2, t3), make_float4(t4, t5, t6, t7));
    }

    f32x4 snD[4];
#pragma unroll
    for (int t = 0; t < 4; ++t) {
        f32x4 acc = {0.f, 0.f, 0.f, 0.f};
        acc = MFMA16(psA[0], loadB(pWps, t, 0, l), acc);
        acc = MFMA16(psA[1], loadB(pWps, t, 1, l), acc);
        snD[t] = acc;
    }
    if (has_skip) {
        const unsigned short* srow = s + (size_t)(i16 + cl) * 64;
        short8 Ai0 = *(const short8*)(srow + q * 8);
        short8 Ai1 = *(const short8*)(srow + 32 + q * 8);
        int myz = spec_srt[i16 + cl];
        for (int z = z0; z <= z1; ++z) {
            bool keep = (myz == z);
            short8 m0 = keep ? Ai0 : z8;
            short8 m1 = keep ? Ai1 : z8;
            const short* pz = pSkS + (size_t)z * 4096;
#pragma unroll
            for (int t = 0; t < 4; ++t) {
                snD[t] = MFMA16(m0, loadB(pz, t, 0, l), snD[t]);
                snD[t] = MFMA16(m1, loadB(pz, t, 1, l), snD[t]);
            }
        }
    }
#pragma unroll
    for (int t = 0; t < 4; ++t)
#pragma unroll
        for (int r = 0; r < 4; ++r)
            s[(size_t)(i16 + q * 4 + r) * 64 + t * 16 + cl] = f2bf(snD[t][r]);

    // ---- fused readout (pre-rounded fp32 registers)
    if (it == 0) {
        float w0c[4];
#pragma unroll
        for (int t = 0; t < 4; ++t) w0c[t] = Wread0[t * 16 + cl];
#pragma unroll
        for (int r = 0; r < 4; ++r) {
            float a = snD[0][r] * w0c[0] + snD[1][r] * w0c[1]
                    + snD[2][r] * w0c[2] + snD[3][r] * w0c[3];
            a += __shfl_down(a, 8);
            a += __shfl_down(a, 4);
            a += __shfl_down(a, 2);
            a += __shfl_down(a, 1);
            if (cl == 0) out[(size_t)sidx[i16 + q * 4 + r] * 2 + 0] = a;
        }
    } else {
#pragma unroll
        for (int t = 0; t < 4; ++t)
#pragma unroll
            for (int r = 0; r < 4; ++r)
                xls[(q * 4 + r) * 65 + t * 16 + cl] = snD[t][r];
        float acc4[4] = {0.f, 0.f, 0.f, 0.f};
        for (int g = 0; g < 64; ++g) {
            float wa = Wr1a[g * 16 + cl];
#pragma unroll
            for (int j = 0; j < 4; ++j)
                acc4[j] = fmaf(xls[(q + 4 * j) * 65 + g], wa, acc4[j]);
        }
        float wb = Wr1b[cl];
#pragma unroll
        for (int j = 0; j < 4; ++j) {
            float av = acc4[j];
            float rr = (av / (1.f + expf(-av))) * wb;
            rr += __shfl_down(rr, 8);
            rr += __shfl_down(rr, 4);
            rr += __shfl_down(rr, 2);
            rr += __shfl_down(rr, 1);
            if (cl == 0) out[(size_t)sidx[i16 + q + 4 * j] * 2 + 1] = rr;
        }
    }

    short8 pvA[3][2];
#pragma unroll
    for (int k = 0; k < 3; ++k) {
#pragma unroll
        for (int t = 0; t < 4; ++t)
#pragma unroll
            for (int r = 0; r < 4; ++r)
                xls[(q * 4 + r) * 65 + t * 16 + cl] = pvsD[t][r] * vD[k][t][r];
#pragma unroll
        for (int h = 0; h < 2; ++h) {
            const float* rp = xls + cl * 65 + h * 32 + q * 8;
            float t0 = rp[0], t1 = rp[1], t2 = rp[2], t3 = rp[3];
            float t4 = rp[4], t5 = rp[5], t6 = rp[6], t7 = rp[7];
            pvA[k][h] = cvt8(make_float4(t0, t1, t2, t3), make_float4(t4, t5, t6, t7));
        }
    }

    f32x4 vnD[3][4];
#pragma unroll
    for (int k = 0; k < 3; ++k)
#pragma unroll
        for (int t = 0; t < 4; ++t) vnD[k][t] = (f32x4){0.f, 0.f, 0.f, 0.f};
#pragma unroll
    for (int t = 0; t < 4; ++t)
#pragma unroll
        for (int h = 0; h < 2; ++h) {
            short8 b = loadB(pWpv, t, h, l);
#pragma unroll
            for (int k = 0; k < 3; ++k) vnD[k][t] = MFMA16(pvA[k][h], b, vnD[k][t]);
        }
    if (has_skip) {
        short8 Aiv[3][2];
#pragma unroll
        for (int k = 0; k < 3; ++k) {
            const unsigned short* r = v + ((size_t)(i16 + cl) * 3 + k) * 64;
            Aiv[k][0] = *(const short8*)(r + q * 8);
            Aiv[k][1] = *(const short8*)(r + 32 + q * 8);
        }
        int myz = spec_srt[i16 + cl];
        for (int z = z0; z <= z1; ++z) {
            bool keep = (myz == z);
            const short* pz = pSkV + (size_t)z * 4096;
#pragma unroll
            for (int t = 0; t < 4; ++t)
#pragma unroll
                for (int h = 0; h < 2; ++h) {
                    short8 b = loadB(pz, t, h, l);
#pragma unroll
                    for (int k = 0; k < 3; ++k) {
                        short8 a = keep ? Aiv[k][h] : z8;
                        vnD[k][t] = MFMA16(a, b, vnD[k][t]);
                    }
                }
        }
    }
#pragma unroll
    for (int k = 0; k < 3; ++k)
#pragma unroll
        for (int t = 0; t < 4; ++t)
#pragma unroll
            for (int r = 0; r < 4; ++r)
                v[((size_t)(i16 + q * 4 + r) * 3 + k) * 64 + t * 16 + cl] = f2bf(vnD[k][t][r]);

    // ---- it==0: zero this wave's own agg boundary rows for interaction 1.
    if (it == 0) {
        for (int rr = 0; rr < 16; ++rr) {
            int i = i16 + rr;
            int beg = row_start[i], end = row_start[i + 1];
            bool need = (end == beg) || (end > (((beg >> 4) + 1) << 4));
            if (need) {
                float* as = (float*)agg_s;
                float* av = (float*)agg_v;
                as[(size_t)i * 64 + l] = 0.f;
                av[((size_t)i * 3 + 0) * 64 + l] = 0.f;
                av[((size_t)i * 3 + 1) * 64 + l] = 0.f;
                av[((size_t)i * 3 + 2) * 64 + l] = 0.f;
            }
        }
    }
}

// ---------------------------------------------------------------------------
extern "C" void kernel_launch(void* const* d_in, const int* in_sizes, int n_in,
                              void* d_out, int out_size, void* d_ws, size_t ws_size,
                              hipStream_t stream)
{
    const float* vectors = (const float*)d_in[0];
    const float* embed_s = (const float*)d_in[1];
    const float* Wr      = (const float*)d_in[2];   // [2,8,320]
    const float* Wls     = (const float*)d_in[3];   // [2,64,64]
    const float* Wlv     = (const float*)d_in[4];
    const float* skip_s  = (const float*)d_in[5];   // [10,64,64]
    const float* skip_v  = (const float*)d_in[6];
    const float* pw      = (const float*)d_in[7];   // [2,10,9,64]
    const float* Wps     = (const float*)d_in[8];
    const float* Wpv     = (const float*)d_in[9];
    const float* Wread0  = (const float*)d_in[10];  // [64,1]
    const float* Wr1a    = (const float*)d_in[11];  // [64,16]
    const float* Wr1b    = (const float*)d_in[12];  // [16,1]
    const int* senders   = (const int*)d_in[13];
    const int* receivers = (const int*)d_in[14];
    const int* species   = (const int*)d_in[15];
    float* out = (float*)d_out;

    float* ws = (float*)d_ws;
    float* edata = ws; ws += (size_t)N_EDGES * 16;  // 16 MB (slot-ordered)
    float* agg_s = ws; ws += (size_t)N_NODES * 64;  // 8 MB
    float* agg_v = ws; ws += (size_t)N_NODES * 192; // 24 MB
    unsigned short* s = (unsigned short*)ws; ws += (size_t)N_NODES * 32;  // 4 MB bf16
    unsigned short* v = (unsigned short*)ws; ws += (size_t)N_NODES * 96;  // 12 MB bf16
    int* counts    = (int*)ws; ws += N_NODES;
    int* row_start = (int*)ws; ws += N_NODES + 4;
    int* cursor    = (int*)ws; ws += N_NODES;
    int* edge_ids  = (int*)ws; ws += N_EDGES;
    int* srk       = (int*)ws; ws += N_EDGES;
    int* grp_row   = (int*)ws; ws += N_EDGES / 16;
    int* sidx      = (int*)ws; ws += N_NODES;
    int* rank      = (int*)ws; ws += N_NODES;
    int* spec_srt  = (int*)ws; ws += N_NODES;
    int* lrank_arr = (int*)ws; ws += N_NODES;
    int* counts_blk = (int*)ws; ws += 128 * NSPEC;
    int* off_blk    = (int*)ws; ws += 128 * NSPEC;
    short* packW   = (short*)ws;                    // 224 KB

    // species counting sort (sort1 also zeroes CSR counts)
    sort1_kernel<<<N_NODES / 256, 256, 0, stream>>>(
        species, counts_blk, lrank_arr, counts);
    sort2_kernel<<<1, 640, 0, stream>>>(counts_blk, off_blk);
    sort3_kernel<<<N_NODES / 256, 256, 0, stream>>>(
        species, lrank_arr, off_blk, sidx, rank, spec_srt);

    // receiver CSR in sorted space
    hist_kernel<<<N_EDGES / 256, 256, 0, stream>>>(receivers, rank, counts);
    scan_kernel<<<1, 1024, 0, stream>>>(counts, row_start, cursor);
    scatter_kernel<<<N_EDGES / 256, 256, 0, stream>>>(receivers, rank, cursor, edge_ids);

    // edge features + packed sender rank/species + grp_row (one pass)
    edge_pre_kernel<<<N_EDGES / 256, 256, 0, stream>>>(
        vectors, edge_ids, senders, rank, species, row_start, edata, srk, grp_row);

    // merged prep: weight pack + zero boundary agg rows (i0). No init_s.
    prep_kernel<<<2048, 256, 0, stream>>>(
        Wls, Wlv, Wps, Wpv, skip_s, skip_v, packW, row_start, agg_s, agg_v);

    // interaction 0 (gather reads embed table; node fuses read0 + re-zeroing)
    gather_kernel<1><<<N_EDGES / 32, 64, 0, stream>>>(
        edata, srk, row_start, grp_row, embed_s, s, v, Wr, agg_s, agg_v);
    node_mfma_kernel<<<N_NODES / 64, 256, 0, stream>>>(
        agg_s, agg_v, s, v, packW, 0, pw, spec_srt,
        row_start, sidx, Wread0, Wr1a, Wr1b, out, 0);

    // interaction 1 (bf16 s/v state halves random gather traffic)
    gather_kernel<0><<<N_EDGES / 32, 64, 0, stream>>>(
        edata, srk, row_start, grp_row, embed_s, s, v, Wr + 2560, agg_s, agg_v);
    node_mfma_kernel<<<N_NODES / 64, 256, 0, stream>>>(
        agg_s, agg_v, s, v, packW, 1, pw + 5760, spec_srt,
        row_start, sidx, Wread0, Wr1a, Wr1b, out, 1);
}